// Round 1
// baseline (2083.458 us; speedup 1.0000x reference)
//
#include <hip/hip_runtime.h>

#define TILE 64
#define KSTEP 16

// NT GEMM: C[m,n] = sum_k A[m,k]*B[n,k] (+bias[n])
// A: [M,K] row-major (batched via strideA), B: [N,K] row-major (strideB), C row-major (strideC)
__global__ __launch_bounds__(256) void gemm_nt(
    const float* __restrict__ A, const float* __restrict__ Bm,
    const float* __restrict__ bias, float* __restrict__ C,
    int M, int N, int K, long strideA, long strideB, long strideC)
{
    __shared__ float As[TILE][KSTEP + 1];
    __shared__ float Bs[TILE][KSTEP + 1];
    const int bz = blockIdx.z;
    const float* Ab = A + (long)bz * strideA;
    const float* Bb = Bm + (long)bz * strideB;
    float* Cb = C + (long)bz * strideC;
    const int m0 = blockIdx.y * TILE;
    const int n0 = blockIdx.x * TILE;
    const int t  = threadIdx.x;          // 0..255
    const int tx = t & 15, ty = t >> 4;
    const int lrow = t >> 2;             // 0..63
    const int lk4  = (t & 3) * 4;        // 0,4,8,12

    float acc[4][4] = {};
    for (int kt = 0; kt < K; kt += KSTEP) {
        const float4 av = *(const float4*)&Ab[(long)(m0 + lrow) * K + kt + lk4];
        const float4 bv = *(const float4*)&Bb[(long)(n0 + lrow) * K + kt + lk4];
        As[lrow][lk4+0] = av.x; As[lrow][lk4+1] = av.y; As[lrow][lk4+2] = av.z; As[lrow][lk4+3] = av.w;
        Bs[lrow][lk4+0] = bv.x; Bs[lrow][lk4+1] = bv.y; Bs[lrow][lk4+2] = bv.z; Bs[lrow][lk4+3] = bv.w;
        __syncthreads();
        #pragma unroll
        for (int kk = 0; kk < KSTEP; ++kk) {
            float a[4], bb[4];
            #pragma unroll
            for (int i = 0; i < 4; ++i) a[i] = As[ty*4+i][kk];
            #pragma unroll
            for (int j = 0; j < 4; ++j) bb[j] = Bs[tx*4+j][kk];
            #pragma unroll
            for (int i = 0; i < 4; ++i)
                #pragma unroll
                for (int j = 0; j < 4; ++j)
                    acc[i][j] += a[i] * bb[j];
        }
        __syncthreads();
    }
    #pragma unroll
    for (int i = 0; i < 4; ++i) {
        const long m = m0 + ty*4 + i;
        #pragma unroll
        for (int j = 0; j < 4; ++j) {
            const int n = n0 + tx*4 + j;
            float v = acc[i][j];
            if (bias) v += bias[n];
            Cb[m * N + n] = v;
        }
    }
}

// NN GEMM: C[m,n] = sum_k A[m,k]*B[k,n]
// A: [M,K] row-major (strideA), B: [K,N] row-major (strideB), C row-major (strideC)
__global__ __launch_bounds__(256) void gemm_nn(
    const float* __restrict__ A, const float* __restrict__ Bm,
    float* __restrict__ C, int M, int N, int K,
    long strideA, long strideB, long strideC)
{
    __shared__ float As[TILE][KSTEP + 1];
    __shared__ float Bs[KSTEP][TILE];
    const int bz = blockIdx.z;
    const float* Ab = A + (long)bz * strideA;
    const float* Bb = Bm + (long)bz * strideB;
    float* Cb = C + (long)bz * strideC;
    const int m0 = blockIdx.y * TILE;
    const int n0 = blockIdx.x * TILE;
    const int t  = threadIdx.x;
    const int tx = t & 15, ty = t >> 4;
    const int lrow = t >> 2;             // 0..63 (A tile row)
    const int lk4  = (t & 3) * 4;        // A tile k offset
    const int brow = t >> 4;             // 0..15 (B tile k row)
    const int bn4  = (t & 15) * 4;       // B tile n offset

    float acc[4][4] = {};
    for (int kt = 0; kt < K; kt += KSTEP) {
        const float4 av = *(const float4*)&Ab[(long)(m0 + lrow) * K + kt + lk4];
        As[lrow][lk4+0] = av.x; As[lrow][lk4+1] = av.y; As[lrow][lk4+2] = av.z; As[lrow][lk4+3] = av.w;
        const float4 bv = *(const float4*)&Bb[(long)(kt + brow) * N + n0 + bn4];
        *(float4*)&Bs[brow][bn4] = bv;
        __syncthreads();
        #pragma unroll
        for (int kk = 0; kk < KSTEP; ++kk) {
            float a[4], bb[4];
            #pragma unroll
            for (int i = 0; i < 4; ++i) a[i] = As[ty*4+i][kk];
            #pragma unroll
            for (int j = 0; j < 4; ++j) bb[j] = Bs[kk][tx*4+j];
            #pragma unroll
            for (int i = 0; i < 4; ++i)
                #pragma unroll
                for (int j = 0; j < 4; ++j)
                    acc[i][j] += a[i] * bb[j];
        }
        __syncthreads();
    }
    #pragma unroll
    for (int i = 0; i < 4; ++i) {
        const long m = m0 + ty*4 + i;
        #pragma unroll
        for (int j = 0; j < 4; ++j) {
            const int n = n0 + tx*4 + j;
            Cb[m * N + n] = acc[i][j];
        }
    }
}

// In-place row softmax: one block per row, 256 threads, cols must be 2048.
__global__ __launch_bounds__(256) void softmax_rows(float* __restrict__ S, int cols)
{
    const long row = blockIdx.x;
    float* p = S + row * (long)cols;
    const int t = threadIdx.x;
    const int wid = t >> 6;

    float vals[8];
    float m = -INFINITY;
    #pragma unroll
    for (int i = 0; i < 8; ++i) {
        vals[i] = p[t + i * 256];
        m = fmaxf(m, vals[i]);
    }
    #pragma unroll
    for (int off = 32; off > 0; off >>= 1)
        m = fmaxf(m, __shfl_xor(m, off));
    __shared__ float smax[4], ssum[4];
    if ((t & 63) == 0) smax[wid] = m;
    __syncthreads();
    m = fmaxf(fmaxf(smax[0], smax[1]), fmaxf(smax[2], smax[3]));

    float s = 0.f;
    #pragma unroll
    for (int i = 0; i < 8; ++i) {
        vals[i] = __expf(vals[i] - m);
        s += vals[i];
    }
    #pragma unroll
    for (int off = 32; off > 0; off >>= 1)
        s += __shfl_xor(s, off);
    if ((t & 63) == 0) ssum[wid] = s;
    __syncthreads();
    s = (ssum[0] + ssum[1]) + (ssum[2] + ssum[3]);
    const float inv = 1.0f / s;
    #pragma unroll
    for (int i = 0; i < 8; ++i)
        p[t + i * 256] = vals[i] * inv;
}

extern "C" void kernel_launch(void* const* d_in, const int* in_sizes, int n_in,
                              void* d_out, int out_size, void* d_ws, size_t ws_size,
                              hipStream_t stream)
{
    const float* query = (const float*)d_in[0];  // [B, Nq, D]
    const float* key   = (const float*)d_in[1];  // [Nk, D]
    const float* x     = (const float*)d_in[2];  // [B, Nk, D]
    const float* W     = (const float*)d_in[3];  // [D, D]
    const float* bias  = (const float*)d_in[4];  // [D]

    const int D  = in_sizes[4];                  // 768
    const int Nk = in_sizes[1] / D;              // 2048
    const int B  = in_sizes[2] / (Nk * D);       // 8
    const int Nq = in_sizes[0] / (B * D);        // 2048

    float* out  = (float*)d_out;                 // [B, Nq, D]
    float* attn = out + (long)B * Nq * D;        // [B, Nq, Nk]
    float* qp   = out;  // stage query_proj in the out region (dead after stage 2)

    // 1) qp[bq, e] = query[bq,:] . W[e,:] + bias[e]   (NT, M=B*Nq, N=D, K=D)
    dim3 g1(D / TILE, (B * Nq) / TILE, 1);
    gemm_nt<<<g1, 256, 0, stream>>>(query, W, bias, qp,
                                    B * Nq, D, D, 0L, 0L, 0L);

    // 2) score[b,q,k] = qp[b,q,:] . key[k,:]   (NT per batch, M=Nq, N=Nk, K=D)
    dim3 g2(Nk / TILE, Nq / TILE, B);
    gemm_nt<<<g2, 256, 0, stream>>>(qp, key, nullptr, attn,
                                    Nq, Nk, D, (long)Nq * D, 0L, (long)Nq * Nk);

    // 3) softmax rows in place
    softmax_rows<<<B * Nq, 256, 0, stream>>>(attn, Nk);

    // 4) out[b,q,d] = attn[b,q,:] . x[b,:,d]   (NN per batch, M=Nq, N=D, K=Nk)
    dim3 g4(D / TILE, Nq / TILE, B);
    gemm_nn<<<g4, 256, 0, stream>>>(attn, x, out,
                                    Nq, D, Nk, (long)Nq * Nk, (long)Nk * D, (long)Nq * D);
}

// Round 2
// 528.813 us; speedup vs baseline: 3.9399x; 3.9399x over previous
//
#include <hip/hip_runtime.h>

typedef short s16x8 __attribute__((ext_vector_type(8)));   // 8 bf16 in 4 VGPRs
typedef float f32x4 __attribute__((ext_vector_type(4)));

__device__ __forceinline__ unsigned short f2bf(float f) {
    unsigned int u = __builtin_bit_cast(unsigned int, f);
    u += 0x7FFFu + ((u >> 16) & 1u);           // round-to-nearest-even
    return (unsigned short)(u >> 16);
}
__device__ __forceinline__ float bf2f(unsigned short h) {
    unsigned int u = ((unsigned int)h) << 16;
    return __builtin_bit_cast(float, u);
}

// Byte offset into a [128 rows][32 bf16] LDS tile (row pitch 64B),
// XOR-swizzled at 16B granularity: spreads 16 consecutive rows at fixed
// k-group across all 8 16B slots (2-way max on ds_read_b128).
__device__ __forceinline__ int swz(int row, int kbyte) {
    return (row * 64 + kbyte) ^ (((row >> 1) & 3) << 4);
}

// C[m,n] = sum_k A[m,k] * B[n,k]  (+ bias[n])
// A: [M,K] fp32 row-major. B: if !TRANSB: [N,K] fp32 row-major.
//                            if  TRANSB: [K,N] fp32 row-major (transposed in LDS).
// SPLIT=3: bf16 hi/lo 3-pass (fp32-class accuracy). SPLIT=1: single bf16 pass.
template<int SPLIT, bool TRANSB, bool BIAS>
__global__ __launch_bounds__(256, 1) void mfma_gemm(
    const float* __restrict__ A, const float* __restrict__ Bsrc,
    const float* __restrict__ bias, float* __restrict__ C,
    int M, int N, int K, long strideA, long strideB, long strideC)
{
    constexpr int NB = (SPLIT > 1) ? 2 : 1;   // hi (+ lo) buffers
    __shared__ unsigned short sA[NB][128 * 32];
    __shared__ unsigned short sB[NB][128 * 32];

    const int t  = threadIdx.x;
    const int bz = blockIdx.z;
    const float* Ab = A    + (long)bz * strideA;
    const float* Bb = Bsrc + (long)bz * strideB;
    float*       Cb = C    + (long)bz * strideC;
    const int m0 = blockIdx.y * 128;
    const int n0 = blockIdx.x * 128;

    const int l  = t & 63, w = t >> 6;
    const int rm = (w >> 1) * 64;      // wave row base in tile
    const int cn = (w & 1) * 64;       // wave col base in tile
    const int lr = l & 15;             // fragment row-within-16
    const int kg = (l >> 4) * 16;      // fragment k byte offset (k = kg/2)

    // NT staging assignment: thread -> (row, 16-float k-half)
    const int srow = t >> 1;
    const int skh  = (t & 1) * 16;
    // TRANSB staging assignment: thread -> (n-group of 8, k-pair)
    const int s_ = t & 15;
    const int kp = t >> 4;             // k0 = 2*kp

    f32x4 acc[4][4];
    #pragma unroll
    for (int i = 0; i < 4; ++i)
        #pragma unroll
        for (int j = 0; j < 4; ++j)
            acc[i][j] = (f32x4){0.f, 0.f, 0.f, 0.f};

    for (int kt = 0; kt < K; kt += 32) {
        // ---------------- stage A tile (always NT) ----------------
        {
            const float* p = &Ab[(long)(m0 + srow) * K + kt + skh];
            float f[16];
            #pragma unroll
            for (int q = 0; q < 4; ++q) {
                const float4 v = *(const float4*)(p + 4 * q);
                f[4*q+0] = v.x; f[4*q+1] = v.y; f[4*q+2] = v.z; f[4*q+3] = v.w;
            }
            s16x8 h0, h1, l0, l1;
            #pragma unroll
            for (int q = 0; q < 8; ++q) {
                unsigned short h = f2bf(f[q]);      h0[q] = (short)h;
                if (SPLIT > 1) l0[q] = (short)f2bf(f[q] - bf2f(h));
                unsigned short g = f2bf(f[8 + q]);  h1[q] = (short)g;
                if (SPLIT > 1) l1[q] = (short)f2bf(f[8 + q] - bf2f(g));
            }
            *(s16x8*)((char*)sA[0] + swz(srow, skh * 2))      = h0;
            *(s16x8*)((char*)sA[0] + swz(srow, skh * 2 + 16)) = h1;
            if (SPLIT > 1) {
                *(s16x8*)((char*)sA[1] + swz(srow, skh * 2))      = l0;
                *(s16x8*)((char*)sA[1] + swz(srow, skh * 2 + 16)) = l1;
            }
        }
        // ---------------- stage B tile ----------------
        if (!TRANSB) {
            const float* p = &Bb[(long)(n0 + srow) * K + kt + skh];
            float f[16];
            #pragma unroll
            for (int q = 0; q < 4; ++q) {
                const float4 v = *(const float4*)(p + 4 * q);
                f[4*q+0] = v.x; f[4*q+1] = v.y; f[4*q+2] = v.z; f[4*q+3] = v.w;
            }
            s16x8 h0, h1, l0, l1;
            #pragma unroll
            for (int q = 0; q < 8; ++q) {
                unsigned short h = f2bf(f[q]);      h0[q] = (short)h;
                if (SPLIT > 1) l0[q] = (short)f2bf(f[q] - bf2f(h));
                unsigned short g = f2bf(f[8 + q]);  h1[q] = (short)g;
                if (SPLIT > 1) l1[q] = (short)f2bf(f[8 + q] - bf2f(g));
            }
            *(s16x8*)((char*)sB[0] + swz(srow, skh * 2))      = h0;
            *(s16x8*)((char*)sB[0] + swz(srow, skh * 2 + 16)) = h1;
            if (SPLIT > 1) {
                *(s16x8*)((char*)sB[1] + swz(srow, skh * 2))      = l0;
                *(s16x8*)((char*)sB[1] + swz(srow, skh * 2 + 16)) = l1;
            }
        } else {
            // B source is [K,N]: rows kt+2kp, kt+2kp+1; cols n0 + s_*8 .. +8
            const float* r0 = &Bb[(long)(kt + 2 * kp) * N + n0 + s_ * 8];
            const float* r1 = r0 + N;
            float a0[8], a1[8];
            {
                const float4 u0 = *(const float4*)(r0);
                const float4 u1 = *(const float4*)(r0 + 4);
                const float4 v0 = *(const float4*)(r1);
                const float4 v1 = *(const float4*)(r1 + 4);
                a0[0]=u0.x;a0[1]=u0.y;a0[2]=u0.z;a0[3]=u0.w;
                a0[4]=u1.x;a0[5]=u1.y;a0[6]=u1.z;a0[7]=u1.w;
                a1[0]=v0.x;a1[1]=v0.y;a1[2]=v0.z;a1[3]=v0.w;
                a1[4]=v1.x;a1[5]=v1.y;a1[6]=v1.z;a1[7]=v1.w;
            }
            // transposed packed-dword writes; lane-phase rotation avoids
            // 16-way same-bank collisions across the s_ groups.
            #pragma unroll
            for (int j = 0; j < 8; ++j) {
                const int i  = (j + s_) & 7;
                const int nl = s_ * 8 + i;
                const unsigned int val =
                    (unsigned int)f2bf(a0[i]) | ((unsigned int)f2bf(a1[i]) << 16);
                *(unsigned int*)((char*)sB[0] + swz(nl, 4 * kp)) = val;
            }
        }
        __syncthreads();

        // ---------------- fragments + MFMA ----------------
        s16x8 ah[4], bh[4];
        #pragma unroll
        for (int mi = 0; mi < 4; ++mi)
            ah[mi] = *(const s16x8*)((const char*)sA[0] + swz(rm + mi * 16 + lr, kg));
        #pragma unroll
        for (int nj = 0; nj < 4; ++nj)
            bh[nj] = *(const s16x8*)((const char*)sB[0] + swz(cn + nj * 16 + lr, kg));
        #pragma unroll
        for (int mi = 0; mi < 4; ++mi)
            #pragma unroll
            for (int nj = 0; nj < 4; ++nj)
                acc[mi][nj] = __builtin_amdgcn_mfma_f32_16x16x32_bf16(
                    ah[mi], bh[nj], acc[mi][nj], 0, 0, 0);
        if (SPLIT > 1) {
            s16x8 al[4], bl[4];
            #pragma unroll
            for (int mi = 0; mi < 4; ++mi)
                al[mi] = *(const s16x8*)((const char*)sA[1] + swz(rm + mi * 16 + lr, kg));
            #pragma unroll
            for (int mi = 0; mi < 4; ++mi)
                #pragma unroll
                for (int nj = 0; nj < 4; ++nj)
                    acc[mi][nj] = __builtin_amdgcn_mfma_f32_16x16x32_bf16(
                        al[mi], bh[nj], acc[mi][nj], 0, 0, 0);
            #pragma unroll
            for (int nj = 0; nj < 4; ++nj)
                bl[nj] = *(const s16x8*)((const char*)sB[1] + swz(cn + nj * 16 + lr, kg));
            #pragma unroll
            for (int mi = 0; mi < 4; ++mi)
                #pragma unroll
                for (int nj = 0; nj < 4; ++nj)
                    acc[mi][nj] = __builtin_amdgcn_mfma_f32_16x16x32_bf16(
                        ah[mi], bl[nj], acc[mi][nj], 0, 0, 0);
        }
        __syncthreads();
    }

    // ---------------- epilogue ----------------
    // D layout: col = lane&15, row = (lane>>4)*4 + reg
    #pragma unroll
    for (int mi = 0; mi < 4; ++mi) {
        #pragma unroll
        for (int nj = 0; nj < 4; ++nj) {
            const int row = m0 + rm + mi * 16 + (l >> 4) * 4;
            const int col = n0 + cn + nj * 16 + lr;
            const float badd = BIAS ? bias[col] : 0.f;
            #pragma unroll
            for (int r = 0; r < 4; ++r)
                Cb[(long)(row + r) * N + col] = acc[mi][nj][r] + badd;
        }
    }
}

// In-place row softmax: one block per row, 256 threads, cols = 2048.
__global__ __launch_bounds__(256) void softmax_rows(float* __restrict__ S, int cols)
{
    const long row = blockIdx.x;
    float* p = S + row * (long)cols;
    const int t = threadIdx.x;
    const int wid = t >> 6;

    float vals[8];
    float m = -INFINITY;
    #pragma unroll
    for (int i = 0; i < 8; ++i) {
        vals[i] = p[t + i * 256];
        m = fmaxf(m, vals[i]);
    }
    #pragma unroll
    for (int off = 32; off > 0; off >>= 1)
        m = fmaxf(m, __shfl_xor(m, off));
    __shared__ float smax[4], ssum[4];
    if ((t & 63) == 0) smax[wid] = m;
    __syncthreads();
    m = fmaxf(fmaxf(smax[0], smax[1]), fmaxf(smax[2], smax[3]));

    float s = 0.f;
    #pragma unroll
    for (int i = 0; i < 8; ++i) {
        vals[i] = __expf(vals[i] - m);
        s += vals[i];
    }
    #pragma unroll
    for (int off = 32; off > 0; off >>= 1)
        s += __shfl_xor(s, off);
    if ((t & 63) == 0) ssum[wid] = s;
    __syncthreads();
    s = (ssum[0] + ssum[1]) + (ssum[2] + ssum[3]);
    const float inv = 1.0f / s;
    #pragma unroll
    for (int i = 0; i < 8; ++i)
        p[t + i * 256] = vals[i] * inv;
}

extern "C" void kernel_launch(void* const* d_in, const int* in_sizes, int n_in,
                              void* d_out, int out_size, void* d_ws, size_t ws_size,
                              hipStream_t stream)
{
    const float* query = (const float*)d_in[0];  // [B, Nq, D]
    const float* key   = (const float*)d_in[1];  // [Nk, D]
    const float* x     = (const float*)d_in[2];  // [B, Nk, D]
    const float* W     = (const float*)d_in[3];  // [D, D]
    const float* bias  = (const float*)d_in[4];  // [D]

    const int D  = in_sizes[4];                  // 768
    const int Nk = in_sizes[1] / D;              // 2048
    const int B  = in_sizes[2] / (Nk * D);       // 8
    const int Nq = in_sizes[0] / (B * D);        // 2048

    float* out  = (float*)d_out;                 // [B, Nq, D]
    float* attn = out + (long)B * Nq * D;        // [B, Nq, Nk]
    float* qp   = out;   // stage query_proj in out region (dead before stage 4)

    // 1) qp = query @ W^T + b       (hi/lo 3-pass)
    dim3 g1(D / 128, (B * Nq) / 128, 1);
    mfma_gemm<3, false, true><<<g1, 256, 0, stream>>>(
        query, W, bias, qp, B * Nq, D, D, 0L, 0L, 0L);

    // 2) score = qp @ key^T per batch   (hi/lo 3-pass)
    dim3 g2(Nk / 128, Nq / 128, B);
    mfma_gemm<3, false, false><<<g2, 256, 0, stream>>>(
        qp, key, nullptr, attn, Nq, Nk, D, (long)Nq * D, 0L, (long)Nq * Nk);

    // 3) softmax rows in place
    softmax_rows<<<B * Nq, 256, 0, stream>>>(attn, Nk);

    // 4) out = attn @ x per batch   (single bf16 pass, B transposed in LDS)
    dim3 g4(D / 128, Nq / 128, B);
    mfma_gemm<1, true, false><<<g4, 256, 0, stream>>>(
        attn, x, nullptr, out, Nq, D, Nk, (long)Nq * Nk, (long)Nk * D, (long)Nq * D);
}

// Round 3
// 383.602 us; speedup vs baseline: 5.4313x; 1.3785x over previous
//
#include <hip/hip_runtime.h>

typedef short s16x8 __attribute__((ext_vector_type(8)));   // 8 bf16 in 4 VGPRs
typedef float f32x4 __attribute__((ext_vector_type(4)));

__device__ __forceinline__ unsigned short f2bf(float f) {
    unsigned int u = __builtin_bit_cast(unsigned int, f);
    u += 0x7FFFu + ((u >> 16) & 1u);           // round-to-nearest-even
    return (unsigned short)(u >> 16);
}
__device__ __forceinline__ float bf2f(unsigned short h) {
    unsigned int u = ((unsigned int)h) << 16;
    return __builtin_bit_cast(float, u);
}

// Byte offset into a [128 rows][32 bf16] LDS tile (row pitch 64B),
// XOR-swizzled at 16B granularity (proven 0 bank conflicts in round 2).
__device__ __forceinline__ int swz(int row, int kbyte) {
    return (row * 64 + kbyte) ^ (((row >> 1) & 3) << 4);
}

// async global->LDS, 16B per lane; LDS dest is wave-uniform base + lane*16.
__device__ __forceinline__ void gl16(const void* g, void* l) {
    __builtin_amdgcn_global_load_lds(
        (__attribute__((address_space(1))) void*)(g),
        (__attribute__((address_space(3))) void*)(l), 16, 0, 0);
}

// ============================================================================
// Round-2 kernel (kept for the tiny KW gemm and as full fallback if ws small)
// ============================================================================
template<int SPLIT, bool TRANSB, bool BIAS>
__global__ __launch_bounds__(256, 1) void mfma_gemm(
    const float* __restrict__ A, const float* __restrict__ Bsrc,
    const float* __restrict__ bias, float* __restrict__ C,
    int M, int N, int K, long strideA, long strideB, long strideC)
{
    constexpr int NB = (SPLIT > 1) ? 2 : 1;
    __shared__ unsigned short sA[NB][128 * 32];
    __shared__ unsigned short sB[NB][128 * 32];

    const int t  = threadIdx.x;
    const int bz = blockIdx.z;
    const float* Ab = A    + (long)bz * strideA;
    const float* Bb = Bsrc + (long)bz * strideB;
    float*       Cb = C    + (long)bz * strideC;
    const int m0 = blockIdx.y * 128;
    const int n0 = blockIdx.x * 128;

    const int l  = t & 63, w = t >> 6;
    const int rm = (w >> 1) * 64;
    const int cn = (w & 1) * 64;
    const int lr = l & 15;
    const int kg = (l >> 4) * 16;

    const int srow = t >> 1;
    const int skh  = (t & 1) * 16;
    const int s_ = t & 15;
    const int kp = t >> 4;

    f32x4 acc[4][4];
    #pragma unroll
    for (int i = 0; i < 4; ++i)
        #pragma unroll
        for (int j = 0; j < 4; ++j)
            acc[i][j] = (f32x4){0.f, 0.f, 0.f, 0.f};

    for (int kt = 0; kt < K; kt += 32) {
        {
            const float* p = &Ab[(long)(m0 + srow) * K + kt + skh];
            float f[16];
            #pragma unroll
            for (int q = 0; q < 4; ++q) {
                const float4 v = *(const float4*)(p + 4 * q);
                f[4*q+0] = v.x; f[4*q+1] = v.y; f[4*q+2] = v.z; f[4*q+3] = v.w;
            }
            s16x8 h0, h1, l0, l1;
            #pragma unroll
            for (int q = 0; q < 8; ++q) {
                unsigned short h = f2bf(f[q]);      h0[q] = (short)h;
                if (SPLIT > 1) l0[q] = (short)f2bf(f[q] - bf2f(h));
                unsigned short g = f2bf(f[8 + q]);  h1[q] = (short)g;
                if (SPLIT > 1) l1[q] = (short)f2bf(f[8 + q] - bf2f(g));
            }
            *(s16x8*)((char*)sA[0] + swz(srow, skh * 2))      = h0;
            *(s16x8*)((char*)sA[0] + swz(srow, skh * 2 + 16)) = h1;
            if (SPLIT > 1) {
                *(s16x8*)((char*)sA[1] + swz(srow, skh * 2))      = l0;
                *(s16x8*)((char*)sA[1] + swz(srow, skh * 2 + 16)) = l1;
            }
        }
        if (!TRANSB) {
            const float* p = &Bb[(long)(n0 + srow) * K + kt + skh];
            float f[16];
            #pragma unroll
            for (int q = 0; q < 4; ++q) {
                const float4 v = *(const float4*)(p + 4 * q);
                f[4*q+0] = v.x; f[4*q+1] = v.y; f[4*q+2] = v.z; f[4*q+3] = v.w;
            }
            s16x8 h0, h1, l0, l1;
            #pragma unroll
            for (int q = 0; q < 8; ++q) {
                unsigned short h = f2bf(f[q]);      h0[q] = (short)h;
                if (SPLIT > 1) l0[q] = (short)f2bf(f[q] - bf2f(h));
                unsigned short g = f2bf(f[8 + q]);  h1[q] = (short)g;
                if (SPLIT > 1) l1[q] = (short)f2bf(f[8 + q] - bf2f(g));
            }
            *(s16x8*)((char*)sB[0] + swz(srow, skh * 2))      = h0;
            *(s16x8*)((char*)sB[0] + swz(srow, skh * 2 + 16)) = h1;
            if (SPLIT > 1) {
                *(s16x8*)((char*)sB[1] + swz(srow, skh * 2))      = l0;
                *(s16x8*)((char*)sB[1] + swz(srow, skh * 2 + 16)) = l1;
            }
        } else {
            const float* r0 = &Bb[(long)(kt + 2 * kp) * N + n0 + s_ * 8];
            const float* r1 = r0 + N;
            float a0[8], a1[8];
            {
                const float4 u0 = *(const float4*)(r0);
                const float4 u1 = *(const float4*)(r0 + 4);
                const float4 v0 = *(const float4*)(r1);
                const float4 v1 = *(const float4*)(r1 + 4);
                a0[0]=u0.x;a0[1]=u0.y;a0[2]=u0.z;a0[3]=u0.w;
                a0[4]=u1.x;a0[5]=u1.y;a0[6]=u1.z;a0[7]=u1.w;
                a1[0]=v0.x;a1[1]=v0.y;a1[2]=v0.z;a1[3]=v0.w;
                a1[4]=v1.x;a1[5]=v1.y;a1[6]=v1.z;a1[7]=v1.w;
            }
            #pragma unroll
            for (int j = 0; j < 8; ++j) {
                const int i  = (j + s_) & 7;
                const int nl = s_ * 8 + i;
                const unsigned int val =
                    (unsigned int)f2bf(a0[i]) | ((unsigned int)f2bf(a1[i]) << 16);
                *(unsigned int*)((char*)sB[0] + swz(nl, 4 * kp)) = val;
            }
        }
        __syncthreads();

        s16x8 ah[4], bh[4];
        #pragma unroll
        for (int mi = 0; mi < 4; ++mi)
            ah[mi] = *(const s16x8*)((const char*)sA[0] + swz(rm + mi * 16 + lr, kg));
        #pragma unroll
        for (int nj = 0; nj < 4; ++nj)
            bh[nj] = *(const s16x8*)((const char*)sB[0] + swz(cn + nj * 16 + lr, kg));
        #pragma unroll
        for (int mi = 0; mi < 4; ++mi)
            #pragma unroll
            for (int nj = 0; nj < 4; ++nj)
                acc[mi][nj] = __builtin_amdgcn_mfma_f32_16x16x32_bf16(
                    ah[mi], bh[nj], acc[mi][nj], 0, 0, 0);
        if (SPLIT > 1) {
            s16x8 al[4], bl[4];
            #pragma unroll
            for (int mi = 0; mi < 4; ++mi)
                al[mi] = *(const s16x8*)((const char*)sA[1] + swz(rm + mi * 16 + lr, kg));
            #pragma unroll
            for (int mi = 0; mi < 4; ++mi)
                #pragma unroll
                for (int nj = 0; nj < 4; ++nj)
                    acc[mi][nj] = __builtin_amdgcn_mfma_f32_16x16x32_bf16(
                        al[mi], bh[nj], acc[mi][nj], 0, 0, 0);
            #pragma unroll
            for (int nj = 0; nj < 4; ++nj)
                bl[nj] = *(const s16x8*)((const char*)sB[1] + swz(cn + nj * 16 + lr, kg));
            #pragma unroll
            for (int mi = 0; mi < 4; ++mi)
                #pragma unroll
                for (int nj = 0; nj < 4; ++nj)
                    acc[mi][nj] = __builtin_amdgcn_mfma_f32_16x16x32_bf16(
                        ah[mi], bl[nj], acc[mi][nj], 0, 0, 0);
        }
        __syncthreads();
    }

    #pragma unroll
    for (int mi = 0; mi < 4; ++mi) {
        #pragma unroll
        for (int nj = 0; nj < 4; ++nj) {
            const int row = m0 + rm + mi * 16 + (l >> 4) * 4;
            const int col = n0 + cn + nj * 16 + lr;
            const float badd = BIAS ? bias[col] : 0.f;
            #pragma unroll
            for (int r = 0; r < 4; ++r)
                Cb[(long)(row + r) * N + col] = acc[mi][nj][r] + badd;
        }
    }
}

// ============================================================================
// score_gemm: C[m,n] = sum_k Ah/l[m,k]*Bh/l[n,k] (3-pass hi/lo) + bias[n]
// A,B pre-converted bf16; staged via global_load_lds with pre-swizzled source.
// Grid: 1-D, nwg = (M/128)*(N/128); XCD-swizzled; nb fastest.
// ============================================================================
__global__ __launch_bounds__(256, 1) void score_gemm(
    const unsigned short* __restrict__ Ah, const unsigned short* __restrict__ Al,
    const unsigned short* __restrict__ Bh, const unsigned short* __restrict__ Bl,
    const float* __restrict__ bias, float* __restrict__ C,
    int M, int N, int K, int nbx)
{
    __shared__ unsigned short sAh[128 * 32];
    __shared__ unsigned short sBh[128 * 32];
    __shared__ unsigned short sAl[128 * 32];
    __shared__ unsigned short sBl[128 * 32];

    const int bid = blockIdx.x;
    const int cpx = gridDim.x >> 3;
    const int sw  = (bid & 7) * cpx + (bid >> 3);   // XCD-contiguous remap
    const int mb  = sw / nbx, nb = sw % nbx;
    const int m0 = mb * 128, n0 = nb * 128;

    const int t = threadIdx.x;
    const int l = t & 63, w = t >> 6;
    const int rm = (w >> 1) * 64;
    const int cn = (w & 1) * 64;
    const int lr = l & 15;
    const int kg = (l >> 4) * 16;

    // staging: wave w covers 1KB regions {2w, 2w+1} of each tile
    const int r0 = 2 * w, r1 = 2 * w + 1;
    const int rowS0 = 16 * r0 + (l >> 2);
    const int rowS1 = 16 * r1 + (l >> 2);
    const int h0 = (l & 3) ^ ((rowS0 >> 1) & 3);    // source pre-swizzle
    const int h1 = (l & 3) ^ ((rowS1 >> 1) & 3);

    const unsigned short* gAh0 = Ah + (long)(m0 + rowS0) * K + 8 * h0;
    const unsigned short* gAh1 = Ah + (long)(m0 + rowS1) * K + 8 * h1;
    const unsigned short* gAl0 = Al + (long)(m0 + rowS0) * K + 8 * h0;
    const unsigned short* gAl1 = Al + (long)(m0 + rowS1) * K + 8 * h1;
    const unsigned short* gBh0 = Bh + (long)(n0 + rowS0) * K + 8 * h0;
    const unsigned short* gBh1 = Bh + (long)(n0 + rowS1) * K + 8 * h1;
    const unsigned short* gBl0 = Bl + (long)(n0 + rowS0) * K + 8 * h0;
    const unsigned short* gBl1 = Bl + (long)(n0 + rowS1) * K + 8 * h1;

    unsigned short* dA0 = &sAh[r0 * 512];
    unsigned short* dA1 = &sAh[r1 * 512];
    unsigned short* dAl0 = &sAl[r0 * 512];
    unsigned short* dAl1 = &sAl[r1 * 512];
    unsigned short* dB0 = &sBh[r0 * 512];
    unsigned short* dB1 = &sBh[r1 * 512];
    unsigned short* dBl0 = &sBl[r0 * 512];
    unsigned short* dBl1 = &sBl[r1 * 512];

    f32x4 acc[4][4];
    #pragma unroll
    for (int i = 0; i < 4; ++i)
        #pragma unroll
        for (int j = 0; j < 4; ++j)
            acc[i][j] = (f32x4){0.f, 0.f, 0.f, 0.f};

    const int nk = K >> 5;
    for (int it = 0; it < nk; ++it) {
        gl16(gAh0, dA0);  gl16(gAh1, dA1);
        gl16(gBh0, dB0);  gl16(gBh1, dB1);
        gl16(gAl0, dAl0); gl16(gAl1, dAl1);
        gl16(gBl0, dBl0); gl16(gBl1, dBl1);
        gAh0 += 32; gAh1 += 32; gAl0 += 32; gAl1 += 32;
        gBh0 += 32; gBh1 += 32; gBl0 += 32; gBl1 += 32;
        __syncthreads();   // drains vmcnt -> staged data visible

        s16x8 ah[4], bh[4];
        #pragma unroll
        for (int mi = 0; mi < 4; ++mi)
            ah[mi] = *(const s16x8*)((const char*)sAh + swz(rm + mi * 16 + lr, kg));
        #pragma unroll
        for (int nj = 0; nj < 4; ++nj)
            bh[nj] = *(const s16x8*)((const char*)sBh + swz(cn + nj * 16 + lr, kg));
        #pragma unroll
        for (int mi = 0; mi < 4; ++mi)
            #pragma unroll
            for (int nj = 0; nj < 4; ++nj)
                acc[mi][nj] = __builtin_amdgcn_mfma_f32_16x16x32_bf16(
                    ah[mi], bh[nj], acc[mi][nj], 0, 0, 0);
        s16x8 al[4], bl[4];
        #pragma unroll
        for (int mi = 0; mi < 4; ++mi)
            al[mi] = *(const s16x8*)((const char*)sAl + swz(rm + mi * 16 + lr, kg));
        #pragma unroll
        for (int mi = 0; mi < 4; ++mi)
            #pragma unroll
            for (int nj = 0; nj < 4; ++nj)
                acc[mi][nj] = __builtin_amdgcn_mfma_f32_16x16x32_bf16(
                    al[mi], bh[nj], acc[mi][nj], 0, 0, 0);
        #pragma unroll
        for (int nj = 0; nj < 4; ++nj)
            bl[nj] = *(const s16x8*)((const char*)sBl + swz(cn + nj * 16 + lr, kg));
        #pragma unroll
        for (int mi = 0; mi < 4; ++mi)
            #pragma unroll
            for (int nj = 0; nj < 4; ++nj)
                acc[mi][nj] = __builtin_amdgcn_mfma_f32_16x16x32_bf16(
                    ah[mi], bl[nj], acc[mi][nj], 0, 0, 0);
        __syncthreads();
    }

    #pragma unroll
    for (int mi = 0; mi < 4; ++mi) {
        #pragma unroll
        for (int nj = 0; nj < 4; ++nj) {
            const int row = m0 + rm + mi * 16 + (l >> 4) * 4;
            const int col = n0 + cn + nj * 16 + lr;
            const float badd = bias[col];
            #pragma unroll
            for (int r = 0; r < 4; ++r)
                C[(long)(row + r) * N + col] = acc[mi][nj][r] + badd;
        }
    }
}

// ============================================================================
// out_gemm: C[m,n] = sum_k A32[m,k]*B16[n,k]; A fp32 (converted to bf16 hi on
// the fly), B bf16 via global_load_lds. Batched over z. Single pass.
// ============================================================================
__global__ __launch_bounds__(256, 1) void out_gemm(
    const float* __restrict__ A32, const unsigned short* __restrict__ B16,
    float* __restrict__ C, int M, int N, int K,
    long strideA, long strideB, long strideC)
{
    __shared__ unsigned short sA[128 * 32];
    __shared__ unsigned short sB[128 * 32];

    const int bz = blockIdx.z;
    const float* Ab = A32 + (long)bz * strideA;
    const unsigned short* Bb = B16 + (long)bz * strideB;
    float* Cb = C + (long)bz * strideC;
    const int m0 = blockIdx.x * 128;   // x = m-block
    const int n0 = blockIdx.y * 128;   // y = n-block

    const int t = threadIdx.x;
    const int l = t & 63, w = t >> 6;
    const int rm = (w >> 1) * 64;
    const int cn = (w & 1) * 64;
    const int lr = l & 15;
    const int kg = (l >> 4) * 16;

    // B staging via gl16
    const int r0 = 2 * w, r1 = 2 * w + 1;
    const int rowS0 = 16 * r0 + (l >> 2);
    const int rowS1 = 16 * r1 + (l >> 2);
    const int h0 = (l & 3) ^ ((rowS0 >> 1) & 3);
    const int h1 = (l & 3) ^ ((rowS1 >> 1) & 3);
    const unsigned short* gB0 = Bb + (long)(n0 + rowS0) * K + 8 * h0;
    const unsigned short* gB1 = Bb + (long)(n0 + rowS1) * K + 8 * h1;
    unsigned short* dB0 = &sB[r0 * 512];
    unsigned short* dB1 = &sB[r1 * 512];

    // A staging (fp32 -> bf16 hi)
    const int srow = t >> 1;
    const int skh  = (t & 1) * 16;
    const float* gA = &Ab[(long)(m0 + srow) * K + skh];

    f32x4 acc[4][4];
    #pragma unroll
    for (int i = 0; i < 4; ++i)
        #pragma unroll
        for (int j = 0; j < 4; ++j)
            acc[i][j] = (f32x4){0.f, 0.f, 0.f, 0.f};

    const int nk = K >> 5;
    for (int it = 0; it < nk; ++it) {
        gl16(gB0, dB0); gl16(gB1, dB1);
        gB0 += 32; gB1 += 32;
        {
            float f[16];
            #pragma unroll
            for (int q = 0; q < 4; ++q) {
                const float4 v = *(const float4*)(gA + 4 * q);
                f[4*q+0] = v.x; f[4*q+1] = v.y; f[4*q+2] = v.z; f[4*q+3] = v.w;
            }
            gA += 32;
            s16x8 v0, v1;
            #pragma unroll
            for (int q = 0; q < 8; ++q) {
                v0[q] = (short)f2bf(f[q]);
                v1[q] = (short)f2bf(f[8 + q]);
            }
            *(s16x8*)((char*)sA + swz(srow, skh * 2))      = v0;
            *(s16x8*)((char*)sA + swz(srow, skh * 2 + 16)) = v1;
        }
        __syncthreads();

        s16x8 ah[4], bh[4];
        #pragma unroll
        for (int mi = 0; mi < 4; ++mi)
            ah[mi] = *(const s16x8*)((const char*)sA + swz(rm + mi * 16 + lr, kg));
        #pragma unroll
        for (int nj = 0; nj < 4; ++nj)
            bh[nj] = *(const s16x8*)((const char*)sB + swz(cn + nj * 16 + lr, kg));
        #pragma unroll
        for (int mi = 0; mi < 4; ++mi)
            #pragma unroll
            for (int nj = 0; nj < 4; ++nj)
                acc[mi][nj] = __builtin_amdgcn_mfma_f32_16x16x32_bf16(
                    ah[mi], bh[nj], acc[mi][nj], 0, 0, 0);
        __syncthreads();
    }

    #pragma unroll
    for (int mi = 0; mi < 4; ++mi) {
        #pragma unroll
        for (int nj = 0; nj < 4; ++nj) {
            const int row = m0 + rm + mi * 16 + (l >> 4) * 4;
            const int col = n0 + cn + nj * 16 + lr;
            #pragma unroll
            for (int r = 0; r < 4; ++r)
                Cb[(long)(row + r) * N + col] = acc[mi][nj][r];
        }
    }
}

// ============================================================================
// small helper kernels
// ============================================================================
// 64x64 fp32 transpose; out fp32 or bf16.
template<bool TOBF16>
__global__ __launch_bounds__(256) void transpose64(
    const float* __restrict__ in, void* __restrict__ outv,
    int R, int Cc, long sIn, long sOut)
{
    __shared__ float tl[64][65];
    const int z = blockIdx.z;
    const float* ib = in + (long)z * sIn;
    const int r0 = blockIdx.x * 64, c0 = blockIdx.y * 64;
    const int t = threadIdx.x;
    const int lrr = t >> 4, lc = (t & 15) * 4;
    #pragma unroll
    for (int p = 0; p < 4; ++p) {
        const float4 v = *(const float4*)&ib[(long)(r0 + lrr + 16 * p) * Cc + c0 + lc];
        tl[lrr + 16 * p][lc + 0] = v.x; tl[lrr + 16 * p][lc + 1] = v.y;
        tl[lrr + 16 * p][lc + 2] = v.z; tl[lrr + 16 * p][lc + 3] = v.w;
    }
    __syncthreads();
    #pragma unroll
    for (int p = 0; p < 4; ++p) {
        const int orow = c0 + lrr + 16 * p;
        const int ocol = r0 + lc;
        const float a = tl[lc + 0][lrr + 16 * p];
        const float b = tl[lc + 1][lrr + 16 * p];
        const float c = tl[lc + 2][lrr + 16 * p];
        const float d = tl[lc + 3][lrr + 16 * p];
        if (TOBF16) {
            ushort4 u = { f2bf(a), f2bf(b), f2bf(c), f2bf(d) };
            *(ushort4*)((unsigned short*)outv + (long)z * sOut + (long)orow * R + ocol) = u;
        } else {
            float4 u = { a, b, c, d };
            *(float4*)((float*)outv + (long)z * sOut + (long)orow * R + ocol) = u;
        }
    }
}

// fp32 -> bf16 hi/lo split, 8 elements per thread, grid-stride.
__global__ __launch_bounds__(256) void convert_hilo(
    const float* __restrict__ src, unsigned short* __restrict__ hi,
    unsigned short* __restrict__ lo, long n8)
{
    for (long i = (long)blockIdx.x * blockDim.x + threadIdx.x; i < n8;
         i += (long)gridDim.x * blockDim.x) {
        const float4 a = *(const float4*)&src[i * 8];
        const float4 b = *(const float4*)&src[i * 8 + 4];
        const float f[8] = { a.x, a.y, a.z, a.w, b.x, b.y, b.z, b.w };
        s16x8 h, lv;
        #pragma unroll
        for (int q = 0; q < 8; ++q) {
            const unsigned short hh = f2bf(f[q]);
            h[q]  = (short)hh;
            lv[q] = (short)f2bf(f[q] - bf2f(hh));
        }
        *(s16x8*)&hi[i * 8] = h;
        *(s16x8*)&lo[i * 8] = lv;
    }
}

// bk[k] = sum_e key[k,e] * b[e]; one wave per row.
__global__ __launch_bounds__(256) void bk_dot(
    const float* __restrict__ key, const float* __restrict__ b,
    float* __restrict__ bk, int D)
{
    const int row = blockIdx.x * 4 + (threadIdx.x >> 6);
    const int l = threadIdx.x & 63;
    const float* kr = key + (long)row * D;
    float s = 0.f;
    for (int e = l; e < D; e += 64) s += kr[e] * b[e];
    #pragma unroll
    for (int off = 32; off > 0; off >>= 1) s += __shfl_xor(s, off);
    if (l == 0) bk[row] = s;
}

// In-place row softmax, cols = 2048.
__global__ __launch_bounds__(256) void softmax_rows(float* __restrict__ S, int cols)
{
    const long row = blockIdx.x;
    float* p = S + row * (long)cols;
    const int t = threadIdx.x;
    const int wid = t >> 6;

    float vals[8];
    float m = -INFINITY;
    #pragma unroll
    for (int i = 0; i < 8; ++i) {
        vals[i] = p[t + i * 256];
        m = fmaxf(m, vals[i]);
    }
    #pragma unroll
    for (int off = 32; off > 0; off >>= 1)
        m = fmaxf(m, __shfl_xor(m, off));
    __shared__ float smax[4], ssum[4];
    if ((t & 63) == 0) smax[wid] = m;
    __syncthreads();
    m = fmaxf(fmaxf(smax[0], smax[1]), fmaxf(smax[2], smax[3]));

    float s = 0.f;
    #pragma unroll
    for (int i = 0; i < 8; ++i) {
        vals[i] = __expf(vals[i] - m);
        s += vals[i];
    }
    #pragma unroll
    for (int off = 32; off > 0; off >>= 1)
        s += __shfl_xor(s, off);
    if ((t & 63) == 0) ssum[wid] = s;
    __syncthreads();
    s = (ssum[0] + ssum[1]) + (ssum[2] + ssum[3]);
    const float inv = 1.0f / s;
    #pragma unroll
    for (int i = 0; i < 8; ++i)
        p[t + i * 256] = vals[i] * inv;
}

// ============================================================================
extern "C" void kernel_launch(void* const* d_in, const int* in_sizes, int n_in,
                              void* d_out, int out_size, void* d_ws, size_t ws_size,
                              hipStream_t stream)
{
    const float* query = (const float*)d_in[0];  // [B, Nq, D]
    const float* key   = (const float*)d_in[1];  // [Nk, D]
    const float* x     = (const float*)d_in[2];  // [B, Nk, D]
    const float* W     = (const float*)d_in[3];  // [D, D]
    const float* bias  = (const float*)d_in[4];  // [D]

    const int D  = in_sizes[4];                  // 768
    const int Nk = in_sizes[1] / D;              // 2048
    const int B  = in_sizes[2] / (Nk * D);       // 8
    const int Nq = in_sizes[0] / (B * D);        // 2048

    float* out  = (float*)d_out;                 // [B, Nq, D]
    float* attn = out + (long)B * Nq * D;        // [B, Nq, Nk]

    const long nQ  = (long)B * Nq * D;           // 12,582,912
    const long nKW = (long)Nk * D;               // 1,572,864
    const size_t wsNeed = (size_t)nQ * 2 * 2;    // q_lo + xT (bf16 each)

    if (ws_size >= wsNeed) {
        // ---------------- fast path ----------------
        // out region: [q_hi | KW_hi | KW_lo | bk]
        unsigned short* q_hi  = (unsigned short*)out;
        unsigned short* KW_hi = q_hi + nQ;
        unsigned short* KW_lo = KW_hi + nKW;
        float*          bk    = (float*)(KW_lo + nKW);
        // ws: [q_lo | xT]
        unsigned short* q_lo  = (unsigned short*)d_ws;
        unsigned short* xT    = q_lo + nQ;
        // attn region scratch (dead before score write): [Wt | KWf]
        float* Wt  = attn;
        float* KWf = attn + 1048576;

        // 1) Wt = W^T
        dim3 gtw(D / 64, D / 64, 1);
        transpose64<false><<<gtw, 256, 0, stream>>>(W, Wt, D, D, 0L, 0L);
        // 2) KWf = key @ Wt^T  (= key @ W)
        dim3 gkw(D / 128, Nk / 128, 1);
        mfma_gemm<3, false, false><<<gkw, 256, 0, stream>>>(
            key, Wt, nullptr, KWf, Nk, D, D, 0L, 0L, 0L);
        // 3) KW hi/lo
        convert_hilo<<<768, 256, 0, stream>>>(KWf, KW_hi, KW_lo, nKW / 8);
        // 4) bk = key @ b
        bk_dot<<<Nk / 4, 256, 0, stream>>>(key, bias, bk, D);
        // 5) q hi/lo
        convert_hilo<<<2048, 256, 0, stream>>>(query, q_hi, q_lo, nQ / 8);
        // 6) xT = x^T (bf16), per batch
        dim3 gtx(Nk / 64, D / 64, B);
        transpose64<true><<<gtx, 256, 0, stream>>>(
            x, xT, Nk, D, (long)Nk * D, (long)D * Nk);
        // 7) scores = q @ KW^T + bk  -> attn region
        const int nbx = Nk / 128;                        // 16
        const int nwg = (B * Nq / 128) * nbx;            // 2048
        score_gemm<<<nwg, 256, 0, stream>>>(
            q_hi, q_lo, KW_hi, KW_lo, bk, attn, B * Nq, Nk, D, nbx);
        // 8) softmax
        softmax_rows<<<B * Nq, 256, 0, stream>>>(attn, Nk);
        // 9) out = attn @ x  (B = xT, NT)
        dim3 go(Nq / 128, D / 128, B);
        out_gemm<<<go, 256, 0, stream>>>(
            attn, xT, out, Nq, D, Nk, (long)Nq * Nk, (long)D * Nk, (long)Nq * D);
    } else {
        // ---------------- fallback: round-2 path ----------------
        float* qp = out;
        dim3 g1(D / 128, (B * Nq) / 128, 1);
        mfma_gemm<3, false, true><<<g1, 256, 0, stream>>>(
            query, W, bias, qp, B * Nq, D, D, 0L, 0L, 0L);
        dim3 g2(Nk / 128, Nq / 128, B);
        mfma_gemm<3, false, false><<<g2, 256, 0, stream>>>(
            qp, key, nullptr, attn, Nq, Nk, D, (long)Nq * D, 0L, (long)Nq * Nk);
        softmax_rows<<<B * Nq, 256, 0, stream>>>(attn, Nk);
        dim3 g4(D / 128, Nq / 128, B);
        mfma_gemm<1, true, false><<<g4, 256, 0, stream>>>(
            attn, x, nullptr, out, Nq, D, Nk, (long)Nq * Nk, (long)Nk * D, (long)Nq * D);
    }
}